// Round 1
// baseline (1678.806 us; speedup 1.0000x reference)
//
#include <hip/hip_runtime.h>
#include <math.h>

// Problem constants
#define B_   2
#define T_   2048
#define D_   1024
#define C_   10
#define F_   513
#define NTOK (B_ * T_)     // 4096 rows
#define LF   3078          // Fall stride = 6*F_ : [qR qI kR kI vR vI]
#define KP   1040          // padded K for output GEMM (Rcat / MoutT stride)
#define OIM  520           // Im column offset inside Rcat/MoutT
#define NCH  128           // scan chunks
#define TC   (T_ / NCH)    // 16 timesteps per chunk

// Workspace layout in floats
#define O_MALL 0
#define SZ_MALL (LF * D_)            // 3,151,872
#define O_MOUT (O_MALL + SZ_MALL)
#define SZ_MOUT (D_ * KP)            // 1,064,960
#define O_RCAT (O_MOUT + SZ_MOUT)
#define SZ_RCAT (NTOK * KP)          // 4,259,840
#define O_FALL (O_RCAT + SZ_RCAT)
#define SZ_FALL (NTOK * LF)          // 12,607,488
#define O_S    (O_FALL + SZ_FALL)
#define SZ_S   (C_ * B_ * NCH * F_ * 2) // 2,626,560
// total = 23,710,720 floats = ~94.8 MB of d_ws

// ---------------------------------------------------------------------------
// Builder 1: Mall[p*513+f][d] = sign_p * sum_e trig(2*pi*f*e/1024) * W_p[e][d]
// p: 0 qR(cos) 1 qI(-sin) 2 kR 3 kI 4 vR 5 vI
// ---------------------------------------------------------------------------
__global__ void hrr_build_mall(const float* __restrict__ Wq,
                               const float* __restrict__ Wk,
                               const float* __restrict__ Wv,
                               float* __restrict__ Mall) {
    const int p  = blockIdx.z;           // 0..5
    const int f0 = blockIdx.y * 16;
    const int d0 = blockIdx.x * 64;
    const float* W = (p < 2) ? Wq : (p < 4) ? Wk : Wv;
    const bool isin = (p & 1);

    __shared__ float tab[1024];
    for (int j = threadIdx.x; j < 1024; j += 256) {
        double ang = (double)j * (M_PI / 512.0);   // 2*pi*j/1024
        tab[j] = (float)(isin ? sin(ang) : cos(ang));
    }
    __syncthreads();

    const int d  = d0 + (threadIdx.x & 63);
    const int fg = threadIdx.x >> 6;          // wave id -> uniform rows per wave
    float acc[4] = {0.f, 0.f, 0.f, 0.f};
    int fr[4], idx[4];
#pragma unroll
    for (int k = 0; k < 4; k++) { fr[k] = f0 + fg * 4 + k; idx[k] = 0; }

    for (int e = 0; e < 1024; e++) {
        float wv = W[e * D_ + d];
#pragma unroll
        for (int k = 0; k < 4; k++) {
            acc[k] += tab[idx[k]] * wv;
            idx[k] = (idx[k] + fr[k]) & 1023;   // (f*e) mod 1024, incremental
        }
    }
    const float sign = isin ? -1.f : 1.f;
#pragma unroll
    for (int k = 0; k < 4; k++)
        if (fr[k] < F_) Mall[(p * F_ + fr[k]) * D_ + d] = sign * acc[k];
}

// ---------------------------------------------------------------------------
// Builder 2 (transposed): MoutT[d'][col] = scale * sum_d trig(2*pi*f*d/1024)*Wo[d'][d]
// p=0: cos, col=f, scale=+w_f/D ; p=1: sin, col=OIM+f, scale=-w_f/D
// ---------------------------------------------------------------------------
__global__ void hrr_build_mout(const float* __restrict__ Wo,
                               float* __restrict__ MoutT) {
    const int p  = blockIdx.z;               // 0..1
    const int f0 = blockIdx.y * 64;
    const int r0 = blockIdx.x * 16;

    __shared__ float tab[1024];
    for (int j = threadIdx.x; j < 1024; j += 256) {
        double ang = (double)j * (M_PI / 512.0);
        tab[j] = (float)(p ? sin(ang) : cos(ang));
    }
    __syncthreads();

    const int f  = f0 + (threadIdx.x & 63);
    const int rg = threadIdx.x >> 6;         // uniform per wave
    const int fw = (f < F_) ? f : 0;
    float acc[4] = {0.f, 0.f, 0.f, 0.f};
    int idx = 0;
#pragma unroll 4
    for (int d = 0; d < 1024; d++) {
        float tv = tab[idx];
        idx = (idx + fw) & 1023;
#pragma unroll
        for (int k = 0; k < 4; k++) {
            int r = r0 + rg * 4 + k;
            acc[k] += tv * Wo[r * D_ + d];
        }
    }
    if (f < F_) {
        float scale = (f == 0 || f == 512) ? (1.0f / 1024.0f) : (2.0f / 1024.0f);
        if (p) scale = -scale;
        const int col = p ? (OIM + f) : f;
#pragma unroll
        for (int k = 0; k < 4; k++) {
            int r = r0 + rg * 4 + k;
            MoutT[r * KP + col] = scale * acc[k];
        }
    }
}

// ---------------------------------------------------------------------------
// fp32 tiled GEMM: C(MxN) = A(MxK, row-major) @ B(NxK, row-major)^T
// 64x64 block tile, 256 threads, 4x4 micro-tile, K-step 16.
// M and K must be multiples of 64/16; N guarded.
// ---------------------------------------------------------------------------
__global__ void hrr_gemm_abt(const float* __restrict__ A,
                             const float* __restrict__ B,
                             float* __restrict__ C,
                             int N, int K, int lda, int ldb, int ldc) {
    __shared__ float As[16][68];
    __shared__ float Bs[16][68];
    const int tx = threadIdx.x & 15;
    const int ty = threadIdx.x >> 4;
    const int bm = blockIdx.y * 64;
    const int bn = blockIdx.x * 64;
    const int lr = threadIdx.x >> 2;          // 0..63 tile row for staging
    const int lk = (threadIdx.x & 3) * 4;     // 0,4,8,12

    float acc[4][4] = {};

    for (int k0 = 0; k0 < K; k0 += 16) {
        float4 a4 = *(const float4*)(A + (size_t)(bm + lr) * lda + k0 + lk);
        float4 b4 = make_float4(0.f, 0.f, 0.f, 0.f);
        if (bn + lr < N)
            b4 = *(const float4*)(B + (size_t)(bn + lr) * ldb + k0 + lk);
        __syncthreads();   // previous iteration finished reading LDS
        As[lk + 0][lr] = a4.x; As[lk + 1][lr] = a4.y;
        As[lk + 2][lr] = a4.z; As[lk + 3][lr] = a4.w;
        Bs[lk + 0][lr] = b4.x; Bs[lk + 1][lr] = b4.y;
        Bs[lk + 2][lr] = b4.z; Bs[lk + 3][lr] = b4.w;
        __syncthreads();
#pragma unroll
        for (int kk = 0; kk < 16; kk++) {
            float4 av = *(const float4*)(&As[kk][ty * 4]);
            float4 bv = *(const float4*)(&Bs[kk][tx * 4]);
            float aa[4] = {av.x, av.y, av.z, av.w};
            float bb[4] = {bv.x, bv.y, bv.z, bv.w};
#pragma unroll
            for (int i = 0; i < 4; i++)
#pragma unroll
                for (int j = 0; j < 4; j++)
                    acc[i][j] += aa[i] * bb[j];
        }
    }
#pragma unroll
    for (int i = 0; i < 4; i++) {
        int m = bm + ty * 4 + i;
#pragma unroll
        for (int j = 0; j < 4; j++) {
            int n = bn + tx * 4 + j;
            if (n < N) C[(size_t)m * ldc + n] = acc[i][j];
        }
    }
}

// ---------------------------------------------------------------------------
// Scan phase 1: chunk sums  S[c][b][n][f] = sum_{t in chunk n} fk[t][g]*fv[t][f]
// One block per (n,b); thread handles (c,f) pairs tid, tid+256, ...
// ---------------------------------------------------------------------------
__global__ void hrr_scan_sums(const float* __restrict__ Fall,
                              const int* __restrict__ perms,
                              float* __restrict__ S) {
    const int n = blockIdx.x, b = blockIdx.y;
    const int tid = threadIdx.x;
    __shared__ float kR[F_], kI[F_], vR[F_], vI[F_];

    float aR[21], aI[21];
    int ff[21], gg[21];
#pragma unroll
    for (int i = 0; i < 21; i++) {
        int p = tid + i * 256;
        aR[i] = aI[i] = 0.f;
        if (p < C_ * F_) {
            int c = p / F_, f = p % F_;
            ff[i] = f; gg[i] = perms[c * F_ + f];
        } else { ff[i] = 0; gg[i] = 0; }
    }

    for (int tl = 0; tl < TC; tl++) {
        const int tt = b * T_ + n * TC + tl;
        const float* row = Fall + (size_t)tt * LF;
        __syncthreads();
        for (int j = tid; j < F_; j += 256) {
            kR[j] = row[2 * F_ + j]; kI[j] = row[3 * F_ + j];
            vR[j] = row[4 * F_ + j]; vI[j] = row[5 * F_ + j];
        }
        __syncthreads();
#pragma unroll
        for (int i = 0; i < 21; i++) {
            int p = tid + i * 256;
            if (p < C_ * F_) {
                float ar = kR[gg[i]], ai = kI[gg[i]];
                float br = vR[ff[i]], bi = vI[ff[i]];
                aR[i] += ar * br - ai * bi;
                aI[i] += ar * bi + ai * br;
            }
        }
    }
#pragma unroll
    for (int i = 0; i < 21; i++) {
        int p = tid + i * 256;
        if (p < C_ * F_) {
            int c = p / F_;
            size_t a = ((((size_t)c * B_ + b) * NCH + n) * F_ + ff[i]) * 2;
            S[a] = aR[i]; S[a + 1] = aI[i];
        }
    }
}

// ---------------------------------------------------------------------------
// Scan phase 2: exclusive prefix over chunks, per (c,b,f). In place.
// ---------------------------------------------------------------------------
__global__ void hrr_scan_prefix(float* __restrict__ S) {
    int tid = blockIdx.x * 256 + threadIdx.x;
    if (tid >= C_ * B_ * F_) return;
    int c = tid / (B_ * F_);
    int r = tid % (B_ * F_);
    int b = r / F_, f = r % F_;
    size_t base = (((size_t)c * B_ + b) * NCH) * F_ + f;
    float runR = 0.f, runI = 0.f;
    for (int n = 0; n < NCH; n++) {
        size_t a = (base + (size_t)n * F_) * 2;
        float tR = S[a], tI = S[a + 1];
        S[a] = runR; S[a + 1] = runI;
        runR += tR; runI += tI;
    }
}

// ---------------------------------------------------------------------------
// Scan phase 3: running kv state (regs) + r = mean_c kv*conj(fqp) -> Rcat
// Thread owns f in {tid, tid+256, tid+512(guarded)} with ALL c copies.
// ---------------------------------------------------------------------------
__global__ void hrr_scan_apply(const float* __restrict__ Fall,
                               const int* __restrict__ perms,
                               const float* __restrict__ S,
                               float* __restrict__ Rcat) {
    const int n = blockIdx.x, b = blockIdx.y;
    const int tid = threadIdx.x;
    __shared__ float qR[F_], qI[F_], kR[F_], kI[F_], vR[F_], vI[F_];

    float kvR[3][C_], kvI[3][C_];
    int gg[3][C_];
#pragma unroll
    for (int i = 0; i < 3; i++) {
        int f = tid + i * 256;
        bool act = (f < F_);
#pragma unroll
        for (int c = 0; c < C_; c++) {
            gg[i][c] = act ? perms[c * F_ + f] : 0;
            if (act) {
                size_t a = ((((size_t)c * B_ + b) * NCH + n) * F_ + f) * 2;
                kvR[i][c] = S[a]; kvI[i][c] = S[a + 1];
            } else { kvR[i][c] = 0.f; kvI[i][c] = 0.f; }
        }
    }

    for (int tl = 0; tl < TC; tl++) {
        const int tt = b * T_ + n * TC + tl;
        const float* row = Fall + (size_t)tt * LF;
        __syncthreads();
        for (int j = tid; j < F_; j += 256) {
            qR[j] = row[j];           qI[j] = row[F_ + j];
            kR[j] = row[2 * F_ + j];  kI[j] = row[3 * F_ + j];
            vR[j] = row[4 * F_ + j];  vI[j] = row[5 * F_ + j];
        }
        __syncthreads();
        float* out = Rcat + (size_t)tt * KP;
#pragma unroll
        for (int i = 0; i < 3; i++) {
            int f = tid + i * 256;
            if (f < F_) {
                float vr = vR[f], vi = vI[f];
                float accR = 0.f, accI = 0.f;
#pragma unroll
                for (int c = 0; c < C_; c++) {
                    int g = gg[i][c];
                    float ar = kR[g], ai = kI[g];
                    float nR = kvR[i][c] + ar * vr - ai * vi;
                    float nI = kvI[i][c] + ar * vi + ai * vr;
                    kvR[i][c] = nR; kvI[i][c] = nI;
                    float qr = qR[g], qi = qI[g];
                    accR += nR * qr + nI * qi;
                    accI += nI * qr - nR * qi;
                }
                out[f] = accR * 0.1f;          // 1/C
                out[OIM + f] = accI * 0.1f;
            }
        }
    }
}

// ---------------------------------------------------------------------------
extern "C" void kernel_launch(void* const* d_in, const int* in_sizes, int n_in,
                              void* d_out, int out_size, void* d_ws, size_t ws_size,
                              hipStream_t stream) {
    const float* x  = (const float*)d_in[0];
    const float* Wq = (const float*)d_in[1];
    const float* Wk = (const float*)d_in[2];
    const float* Wv = (const float*)d_in[3];
    const float* Wo = (const float*)d_in[4];
    const int* perms = (const int*)d_in[5];
    float* out = (float*)d_out;

    float* ws = (float*)d_ws;
    float* Mall  = ws + O_MALL;
    float* MoutT = ws + O_MOUT;
    float* Rcat  = ws + O_RCAT;
    float* Fall  = ws + O_FALL;
    float* S     = ws + O_S;

    // zero MoutT + Rcat (contiguous) so pad columns are 0 (ws is poisoned 0xAA)
    hipMemsetAsync(ws + O_MOUT, 0, (size_t)(SZ_MOUT + SZ_RCAT) * sizeof(float), stream);

    // fused rfft*W projection matrices
    hrr_build_mall<<<dim3(16, 33, 6), 256, 0, stream>>>(Wq, Wk, Wv, Mall);
    // fused irfft*Wo output matrix (transposed, padded to KP)
    hrr_build_mout<<<dim3(64, 9, 2), 256, 0, stream>>>(Wo, MoutT);

    // Fall(4096 x 3078) = x @ Mall^T
    hrr_gemm_abt<<<dim3((LF + 63) / 64, NTOK / 64), 256, 0, stream>>>(
        x, Mall, Fall, LF, D_, D_, D_, LF);

    // chunked causal scan over time
    hrr_scan_sums<<<dim3(NCH, B_), 256, 0, stream>>>(Fall, perms, S);
    hrr_scan_prefix<<<(C_ * B_ * F_ + 255) / 256, 256, 0, stream>>>(S);
    hrr_scan_apply<<<dim3(NCH, B_), 256, 0, stream>>>(Fall, perms, S, Rcat);

    // out(4096 x 1024) = Rcat @ MoutT^T   (irfft + Wo fused)
    hrr_gemm_abt<<<dim3(D_ / 64, NTOK / 64), 256, 0, stream>>>(
        Rcat, MoutT, out, D_, KP, KP, KP, D_);
}

// Round 2
// 1189.503 us; speedup vs baseline: 1.4114x; 1.4114x over previous
//
#include <hip/hip_runtime.h>
#include <math.h>

// Problem constants
#define B_   2
#define T_   2048
#define D_   1024
#define C_   10
#define F_   513
#define NTOK (B_ * T_)     // 4096 rows
#define LF   3078          // Fall stride = 6*F_ : [qR qI kR kI vR vI]
#define KP   1040          // padded K for output GEMM (Rcat / MoutT stride)
#define OIM  520           // Im column offset inside Rcat/MoutT
#define NCH  128           // scan chunks
#define TC   (T_ / NCH)    // 16 timesteps per chunk

// Workspace layout in floats
#define O_MALL 0
#define SZ_MALL (LF * D_)            // 3,151,872
#define O_MOUT (O_MALL + SZ_MALL)
#define SZ_MOUT (D_ * KP)            // 1,064,960
#define O_RCAT (O_MOUT + SZ_MOUT)
#define SZ_RCAT (NTOK * KP)          // 4,259,840
#define O_FALL (O_RCAT + SZ_RCAT)
#define SZ_FALL (NTOK * LF)          // 12,607,488
#define O_S    (O_FALL + SZ_FALL)
#define SZ_S   (C_ * B_ * NCH * F_ * 2) // 2,626,560
// total = 23,710,720 floats = ~94.8 MB of d_ws

// ---------------------------------------------------------------------------
// Builder 1: Mall[p*513+f][d] = sign_p * sum_e trig(2*pi*f*e/1024) * W_p[e][d]
// p: 0 qR(cos) 1 qI(-sin) 2 kR 3 kI 4 vR 5 vI
// ---------------------------------------------------------------------------
__global__ void hrr_build_mall(const float* __restrict__ Wq,
                               const float* __restrict__ Wk,
                               const float* __restrict__ Wv,
                               float* __restrict__ Mall) {
    const int p  = blockIdx.z;           // 0..5
    const int f0 = blockIdx.y * 16;
    const int d0 = blockIdx.x * 64;
    const float* W = (p < 2) ? Wq : (p < 4) ? Wk : Wv;
    const bool isin = (p & 1);

    __shared__ float tab[1024];
    for (int j = threadIdx.x; j < 1024; j += 256) {
        double ang = (double)j * (M_PI / 512.0);   // 2*pi*j/1024
        tab[j] = (float)(isin ? sin(ang) : cos(ang));
    }
    __syncthreads();

    const int d  = d0 + (threadIdx.x & 63);
    const int fg = threadIdx.x >> 6;          // wave id -> uniform rows per wave
    float acc[4] = {0.f, 0.f, 0.f, 0.f};
    int fr[4], idx[4];
#pragma unroll
    for (int k = 0; k < 4; k++) { fr[k] = f0 + fg * 4 + k; idx[k] = 0; }

    for (int e = 0; e < 1024; e++) {
        float wv = W[e * D_ + d];
#pragma unroll
        for (int k = 0; k < 4; k++) {
            acc[k] += tab[idx[k]] * wv;
            idx[k] = (idx[k] + fr[k]) & 1023;   // (f*e) mod 1024, incremental
        }
    }
    const float sign = isin ? -1.f : 1.f;
#pragma unroll
    for (int k = 0; k < 4; k++)
        if (fr[k] < F_) Mall[(p * F_ + fr[k]) * D_ + d] = sign * acc[k];
}

// ---------------------------------------------------------------------------
// Builder 2 (transposed): MoutT[d'][col] = scale * sum_d trig(2*pi*f*d/1024)*Wo[d'][d]
// p=0: cos, col=f, scale=+w_f/D ; p=1: sin, col=OIM+f, scale=-w_f/D
// ---------------------------------------------------------------------------
__global__ void hrr_build_mout(const float* __restrict__ Wo,
                               float* __restrict__ MoutT) {
    const int p  = blockIdx.z;               // 0..1
    const int f0 = blockIdx.y * 64;
    const int r0 = blockIdx.x * 16;

    __shared__ float tab[1024];
    for (int j = threadIdx.x; j < 1024; j += 256) {
        double ang = (double)j * (M_PI / 512.0);
        tab[j] = (float)(p ? sin(ang) : cos(ang));
    }
    __syncthreads();

    const int f  = f0 + (threadIdx.x & 63);
    const int rg = threadIdx.x >> 6;         // uniform per wave
    const int fw = (f < F_) ? f : 0;
    float acc[4] = {0.f, 0.f, 0.f, 0.f};
    int idx = 0;
#pragma unroll 4
    for (int d = 0; d < 1024; d++) {
        float tv = tab[idx];
        idx = (idx + fw) & 1023;
#pragma unroll
        for (int k = 0; k < 4; k++) {
            int r = r0 + rg * 4 + k;
            acc[k] += tv * Wo[r * D_ + d];
        }
    }
    if (f < F_) {
        float scale = (f == 0 || f == 512) ? (1.0f / 1024.0f) : (2.0f / 1024.0f);
        if (p) scale = -scale;
        const int col = p ? (OIM + f) : f;
#pragma unroll
        for (int k = 0; k < 4; k++) {
            int r = r0 + rg * 4 + k;
            MoutT[r * KP + col] = scale * acc[k];
        }
    }
}

// ---------------------------------------------------------------------------
// fp32 tiled GEMM: C(MxN) = A(MxK, row-major) @ B(NxK, row-major)^T
// 64x64 block tile, 256 threads, 4x4 micro-tile, K-step 16.
// M and K must be multiples of 64/16; N guarded.
// ---------------------------------------------------------------------------
__global__ void hrr_gemm_abt(const float* __restrict__ A,
                             const float* __restrict__ B,
                             float* __restrict__ C,
                             int N, int K, int lda, int ldb, int ldc) {
    __shared__ float As[16][68];
    __shared__ float Bs[16][68];
    const int tx = threadIdx.x & 15;
    const int ty = threadIdx.x >> 4;
    const int bm = blockIdx.y * 64;
    const int bn = blockIdx.x * 64;
    const int lr = threadIdx.x >> 2;          // 0..63 tile row for staging
    const int lk = (threadIdx.x & 3) * 4;     // 0,4,8,12

    float acc[4][4] = {};

    for (int k0 = 0; k0 < K; k0 += 16) {
        float4 a4 = *(const float4*)(A + (size_t)(bm + lr) * lda + k0 + lk);
        float4 b4 = make_float4(0.f, 0.f, 0.f, 0.f);
        if (bn + lr < N)
            b4 = *(const float4*)(B + (size_t)(bn + lr) * ldb + k0 + lk);
        __syncthreads();   // previous iteration finished reading LDS
        As[lk + 0][lr] = a4.x; As[lk + 1][lr] = a4.y;
        As[lk + 2][lr] = a4.z; As[lk + 3][lr] = a4.w;
        Bs[lk + 0][lr] = b4.x; Bs[lk + 1][lr] = b4.y;
        Bs[lk + 2][lr] = b4.z; Bs[lk + 3][lr] = b4.w;
        __syncthreads();
#pragma unroll
        for (int kk = 0; kk < 16; kk++) {
            float4 av = *(const float4*)(&As[kk][ty * 4]);
            float4 bv = *(const float4*)(&Bs[kk][tx * 4]);
            float aa[4] = {av.x, av.y, av.z, av.w};
            float bb[4] = {bv.x, bv.y, bv.z, bv.w};
#pragma unroll
            for (int i = 0; i < 4; i++)
#pragma unroll
                for (int j = 0; j < 4; j++)
                    acc[i][j] += aa[i] * bb[j];
        }
    }
#pragma unroll
    for (int i = 0; i < 4; i++) {
        int m = bm + ty * 4 + i;
#pragma unroll
        for (int j = 0; j < 4; j++) {
            int n = bn + tx * 4 + j;
            if (n < N) C[(size_t)m * ldc + n] = acc[i][j];
        }
    }
}

// ---------------------------------------------------------------------------
// Scan phase 1: chunk sums  S[c][b][n][f] = sum_{t in chunk n} fk[t][g]*fv[t][f]
// One block per (n,b,c); thread handles f = tid, tid+256, tid+512 (guarded).
// Only 6 accumulator floats + 3 perm indices per thread -> no spill.
// ---------------------------------------------------------------------------
__global__ void hrr_scan_sums(const float* __restrict__ Fall,
                              const int* __restrict__ perms,
                              float* __restrict__ S) {
    const int n = blockIdx.x, b = blockIdx.y, c = blockIdx.z;
    const int tid = threadIdx.x;
    __shared__ float kR[F_], kI[F_], vR[F_], vI[F_];

    float aR[3] = {0.f, 0.f, 0.f}, aI[3] = {0.f, 0.f, 0.f};
    int gg[3];
#pragma unroll
    for (int i = 0; i < 3; i++) {
        int f = tid + i * 256;
        gg[i] = (f < F_) ? perms[c * F_ + f] : 0;
    }

    for (int tl = 0; tl < TC; tl++) {
        const int tt = b * T_ + n * TC + tl;
        const float* row = Fall + (size_t)tt * LF;
        __syncthreads();
        for (int j = tid; j < F_; j += 256) {
            kR[j] = row[2 * F_ + j]; kI[j] = row[3 * F_ + j];
            vR[j] = row[4 * F_ + j]; vI[j] = row[5 * F_ + j];
        }
        __syncthreads();
#pragma unroll
        for (int i = 0; i < 3; i++) {
            int f = tid + i * 256;
            if (f < F_) {
                float ar = kR[gg[i]], ai = kI[gg[i]];
                float br = vR[f], bi = vI[f];
                aR[i] += ar * br - ai * bi;
                aI[i] += ar * bi + ai * br;
            }
        }
    }
#pragma unroll
    for (int i = 0; i < 3; i++) {
        int f = tid + i * 256;
        if (f < F_) {
            size_t a = ((((size_t)c * B_ + b) * NCH + n) * F_ + f) * 2;
            S[a] = aR[i]; S[a + 1] = aI[i];
        }
    }
}

// ---------------------------------------------------------------------------
// Scan phase 2: exclusive prefix over chunks, per (c,b,f). In place.
// ---------------------------------------------------------------------------
__global__ void hrr_scan_prefix(float* __restrict__ S) {
    int tid = blockIdx.x * 256 + threadIdx.x;
    if (tid >= C_ * B_ * F_) return;
    int c = tid / (B_ * F_);
    int r = tid % (B_ * F_);
    int b = r / F_, f = r % F_;
    size_t base = (((size_t)c * B_ + b) * NCH) * F_ + f;
    float runR = 0.f, runI = 0.f;
    for (int n = 0; n < NCH; n++) {
        size_t a = (base + (size_t)n * F_) * 2;
        float tR = S[a], tI = S[a + 1];
        S[a] = runR; S[a + 1] = runI;
        runR += tR; runI += tI;
    }
}

// ---------------------------------------------------------------------------
// Scan phase 3: running kv state (regs) + r = mean_c kv*conj(fqp) -> Rcat
// 512 threads; thread owns f = tid (thread 0 also owns f = 512).
// Per-thread state: kv[2][C] + perm[2][C] -> ~60 regs, no spill at 128 cap.
// ---------------------------------------------------------------------------
__global__ __launch_bounds__(512, 2)
void hrr_scan_apply(const float* __restrict__ Fall,
                    const int* __restrict__ perms,
                    const float* __restrict__ S,
                    float* __restrict__ Rcat) {
    const int n = blockIdx.x, b = blockIdx.y;
    const int tid = threadIdx.x;
    __shared__ float qR[F_], qI[F_], kR[F_], kI[F_], vR[F_], vI[F_];

    float kvR[2][C_], kvI[2][C_];
    int gg[2][C_];
#pragma unroll
    for (int i = 0; i < 2; i++) {
        const int f = (i == 0) ? tid : 512;
        const bool act = (i == 0) || (tid == 0);
#pragma unroll
        for (int c = 0; c < C_; c++) {
            gg[i][c] = act ? perms[c * F_ + f] : 0;
            if (act) {
                size_t a = ((((size_t)c * B_ + b) * NCH + n) * F_ + f) * 2;
                kvR[i][c] = S[a]; kvI[i][c] = S[a + 1];
            } else { kvR[i][c] = 0.f; kvI[i][c] = 0.f; }
        }
    }

    for (int tl = 0; tl < TC; tl++) {
        const int tt = b * T_ + n * TC + tl;
        const float* row = Fall + (size_t)tt * LF;
        __syncthreads();
        for (int j = tid; j < F_; j += 512) {
            qR[j] = row[j];           qI[j] = row[F_ + j];
            kR[j] = row[2 * F_ + j];  kI[j] = row[3 * F_ + j];
            vR[j] = row[4 * F_ + j];  vI[j] = row[5 * F_ + j];
        }
        __syncthreads();
        float* out = Rcat + (size_t)tt * KP;
#pragma unroll
        for (int i = 0; i < 2; i++) {
            const int f = (i == 0) ? tid : 512;
            if (i == 0 || tid == 0) {
                float vr = vR[f], vi = vI[f];
                float accR = 0.f, accI = 0.f;
#pragma unroll
                for (int c = 0; c < C_; c++) {
                    int g = gg[i][c];
                    float ar = kR[g], ai = kI[g];
                    float nR = kvR[i][c] + ar * vr - ai * vi;
                    float nI = kvI[i][c] + ar * vi + ai * vr;
                    kvR[i][c] = nR; kvI[i][c] = nI;
                    float qr = qR[g], qi = qI[g];
                    accR += nR * qr + nI * qi;
                    accI += nI * qr - nR * qi;
                }
                out[f] = accR * 0.1f;          // 1/C
                out[OIM + f] = accI * 0.1f;
            }
        }
    }
}

// ---------------------------------------------------------------------------
extern "C" void kernel_launch(void* const* d_in, const int* in_sizes, int n_in,
                              void* d_out, int out_size, void* d_ws, size_t ws_size,
                              hipStream_t stream) {
    const float* x  = (const float*)d_in[0];
    const float* Wq = (const float*)d_in[1];
    const float* Wk = (const float*)d_in[2];
    const float* Wv = (const float*)d_in[3];
    const float* Wo = (const float*)d_in[4];
    const int* perms = (const int*)d_in[5];
    float* out = (float*)d_out;

    float* ws = (float*)d_ws;
    float* Mall  = ws + O_MALL;
    float* MoutT = ws + O_MOUT;
    float* Rcat  = ws + O_RCAT;
    float* Fall  = ws + O_FALL;
    float* S     = ws + O_S;

    // zero MoutT + Rcat (contiguous) so pad columns are 0 (ws is poisoned 0xAA)
    hipMemsetAsync(ws + O_MOUT, 0, (size_t)(SZ_MOUT + SZ_RCAT) * sizeof(float), stream);

    // fused rfft*W projection matrices
    hrr_build_mall<<<dim3(16, 33, 6), 256, 0, stream>>>(Wq, Wk, Wv, Mall);
    // fused irfft*Wo output matrix (transposed, padded to KP)
    hrr_build_mout<<<dim3(64, 9, 2), 256, 0, stream>>>(Wo, MoutT);

    // Fall(4096 x 3078) = x @ Mall^T
    hrr_gemm_abt<<<dim3((LF + 63) / 64, NTOK / 64), 256, 0, stream>>>(
        x, Mall, Fall, LF, D_, D_, D_, LF);

    // chunked causal scan over time
    hrr_scan_sums<<<dim3(NCH, B_, C_), 256, 0, stream>>>(Fall, perms, S);
    hrr_scan_prefix<<<(C_ * B_ * F_ + 255) / 256, 256, 0, stream>>>(S);
    hrr_scan_apply<<<dim3(NCH, B_), 512, 0, stream>>>(Fall, perms, S, Rcat);

    // out(4096 x 1024) = Rcat @ MoutT^T   (irfft + Wo fused)
    hrr_gemm_abt<<<dim3(D_ / 64, NTOK / 64), 256, 0, stream>>>(
        Rcat, MoutT, out, D_, KP, KP, KP, D_);
}

// Round 3
// 293.428 us; speedup vs baseline: 5.7214x; 4.0538x over previous
//
#include <hip/hip_runtime.h>
#include <math.h>

// Problem constants
#define B_   2
#define T_   2048
#define D_   1024
#define C_   10
#define F_   513
#define NTOK (B_ * T_)     // 4096 rows
#define LF   3078          // Fall stride = 6*F_ : [qR qI kR kI vR vI]
#define KP2  1056          // padded K for output GEMM (mult of 32)
#define OIM2 528           // Im block offset inside Rcat/MoutT (16-elem aligned)
#define NCH  128           // scan chunks
#define TC   (T_ / NCH)    // 16 timesteps per chunk

typedef unsigned short us16;
typedef __attribute__((ext_vector_type(8))) __bf16 bf16x8;
typedef __attribute__((ext_vector_type(4))) float  f32x4;

// Workspace layout (bytes)
#define O_XBF    ((size_t)0)                       // x bf16: 4096*1024*2 = 8,388,608
#define O_PREP   ((size_t)8388608)                 // WT(3x2MB) + Wo_bf(2MB) + Tcs(2,101,248) = 10,489,856
#define O_WT     (O_PREP)                          //   WT: 3 * 1024*1024*2
#define O_WOBF   (O_PREP + 6291456)                //   Wo bf16
#define O_TCS    (O_PREP + 8388608)                //   Tcs: 1026*1024*2
#define O_RCAT   (O_PREP)                          // Rcat bf16 aliases PREP after builders: 4096*1056*2 = 8,650,752
#define O_SFB    (O_PREP + 10489856)               // S: 1056*1024*2 = 2,162,688
#define O_MALLB  (O_SFB + 2162688)                 // Mall bf16: 3078*1024*2 = 6,303,744
#define O_MOUTB  (O_MALLB + 6303744)               // MoutT bf16: 1024*1056*2 = 2,162,688
#define O_FALL   (O_MOUTB + 2162688)               // Fall fp32: 4096*3078*4 = 50,429,952
#define O_SSCAN  (O_FALL + 50429952)               // scan sums fp32: 10*2*128*513*2*4 = 10,506,240
// total = 90,443,776 bytes (~86.3 MB)

__device__ __forceinline__ us16 f2b(float f) {
    union { float f; unsigned u; } v; v.f = f;
    unsigned r = v.u + 0x7FFFu + ((v.u >> 16) & 1u);
    return (us16)(r >> 16);
}

// ---------------------------------------------------------------------------
// float -> bf16 copy-convert (vectorized by 4)
// ---------------------------------------------------------------------------
__global__ void hrr_cvt_bf16(const float* __restrict__ in, us16* __restrict__ out, int n4) {
    int i = blockIdx.x * 256 + threadIdx.x;
    if (i < n4) {
        float4 v = ((const float4*)in)[i];
        ushort4 o;
        o.x = f2b(v.x); o.y = f2b(v.y); o.z = f2b(v.z); o.w = f2b(v.w);
        ((ushort4*)out)[i] = o;
    }
}

// ---------------------------------------------------------------------------
// Transpose W (1024x1024 fp32) -> bf16, 3 matrices via blockIdx.z
// ---------------------------------------------------------------------------
__global__ void hrr_transpose_bf16(const float* __restrict__ Wq,
                                   const float* __restrict__ Wk,
                                   const float* __restrict__ Wv,
                                   us16* __restrict__ WT) {
    const float* W = (blockIdx.z == 0) ? Wq : (blockIdx.z == 1) ? Wk : Wv;
    us16* O = WT + (size_t)blockIdx.z * D_ * D_;
    __shared__ float t[32][33];
    const int bx = blockIdx.x * 32, by = blockIdx.y * 32;
    const int tx = threadIdx.x & 31, ty = threadIdx.x >> 5;   // 32 x 8
#pragma unroll
    for (int i = 0; i < 32; i += 8)
        t[ty + i][tx] = W[(size_t)(by + ty + i) * D_ + bx + tx];
    __syncthreads();
#pragma unroll
    for (int i = 0; i < 32; i += 8)
        O[(size_t)(bx + ty + i) * D_ + by + tx] = f2b(t[tx][ty + i]);
}

// ---------------------------------------------------------------------------
// Tcs (1026 x 1024 bf16): rows 0..512 = cos(2*pi*f*e/1024); rows 513.. = -sin
// ---------------------------------------------------------------------------
__global__ void hrr_build_tcs(us16* __restrict__ Tcs) {
    int idx = blockIdx.x * 256 + threadIdx.x;
    if (idx >= 1026 * 1024) return;
    int r = idx >> 10, e = idx & 1023;
    int f = (r < F_) ? r : r - F_;
    int m = (f * e) & 1023;
    float ang = (float)m * 6.135923151542565e-3f;   // 2*pi/1024
    float v = (r < F_) ? cosf(ang) : -sinf(ang);
    Tcs[idx] = f2b(v);
}

// ---------------------------------------------------------------------------
// S (1056 x 1024 bf16): rows 0..512 = scale_f*cos ; rows 528..1040 = -scale_f*sin
// (scale_f = (f==0||f==512 ? 1 : 2)/1024, folds irfft weights); pad rows = 0
// ---------------------------------------------------------------------------
__global__ void hrr_build_sfb(us16* __restrict__ S) {
    int idx = blockIdx.x * 256 + threadIdx.x;
    if (idx >= KP2 * 1024) return;
    int r = idx >> 10, e = idx & 1023;
    float v = 0.f;
    if (r < F_) {
        float scale = (r == 0 || r == 512) ? (1.0f / 1024.0f) : (2.0f / 1024.0f);
        v = scale * cosf((float)((r * e) & 1023) * 6.135923151542565e-3f);
    } else if (r >= OIM2 && r < OIM2 + F_) {
        int f = r - OIM2;
        float scale = (f == 0 || f == 512) ? (1.0f / 1024.0f) : (2.0f / 1024.0f);
        v = -scale * sinf((float)((f * e) & 1023) * 6.135923151542565e-3f);
    }
    S[idx] = f2b(v);
}

// ---------------------------------------------------------------------------
// bf16 MFMA GEMM: C(MxN) = A(MxK bf16 row-major) @ B(NxK bf16 row-major)^T
// 128x128 tile, 256 threads (4 waves in 2x2 of 64x64), K-step 32, 16x16x32 MFMA.
// M,N guarded (staging rows clamped; epilogue bounds-checked). K mult of 32,
// lda/ldb mult of 8. OUT_BF16 selects us16 vs float C. Batch via blockIdx.z.
// ---------------------------------------------------------------------------
template <bool OUT_BF16>
__global__ __launch_bounds__(256, 2)
void hrr_gemm_mfma(const us16* __restrict__ Ab, const us16* __restrict__ Bb,
                   void* __restrict__ Cv, int M, int N, int K,
                   int lda, int ldb, int ldc,
                   size_t strideA, size_t strideB, size_t strideC) {
    const us16* A = Ab + strideA * blockIdx.z;
    const us16* B = Bb + strideB * blockIdx.z;

    __shared__ us16 As[128 * 32];
    __shared__ us16 Bs[128 * 32];

    const int tid  = threadIdx.x;
    const int lane = tid & 63;
    const int wave = tid >> 6;
    const int wm = (wave >> 1) * 64;
    const int wn = (wave & 1) * 64;
    const int bm = blockIdx.y * 128;
    const int bn = blockIdx.x * 128;

    f32x4 acc[4][4];
#pragma unroll
    for (int i = 0; i < 4; i++)
#pragma unroll
        for (int j = 0; j < 4; j++) acc[i][j] = (f32x4){0.f, 0.f, 0.f, 0.f};

    const int r0 = tid >> 2;          // 0..63
    const int c4 = (tid & 3) * 8;     // 0,8,16,24 elements

    int rA0 = bm + r0;      if (rA0 >= M) rA0 = M - 1;
    int rA1 = bm + 64 + r0; if (rA1 >= M) rA1 = M - 1;
    int rB0 = bn + r0;      if (rB0 >= N) rB0 = N - 1;
    int rB1 = bn + 64 + r0; if (rB1 >= N) rB1 = N - 1;
    const us16* pA0 = A + (size_t)rA0 * lda + c4;
    const us16* pA1 = A + (size_t)rA1 * lda + c4;
    const us16* pB0 = B + (size_t)rB0 * ldb + c4;
    const us16* pB1 = B + (size_t)rB1 * ldb + c4;

    const int fr = lane & 15;
    const int kg = (lane >> 4) * 8;

    for (int k0 = 0; k0 < K; k0 += 32) {
        uint4 a0 = *(const uint4*)(pA0 + k0);
        uint4 a1 = *(const uint4*)(pA1 + k0);
        uint4 b0 = *(const uint4*)(pB0 + k0);
        uint4 b1 = *(const uint4*)(pB1 + k0);
        __syncthreads();
        *(uint4*)(As + r0 * 32 + c4)        = a0;
        *(uint4*)(As + (64 + r0) * 32 + c4) = a1;
        *(uint4*)(Bs + r0 * 32 + c4)        = b0;
        *(uint4*)(Bs + (64 + r0) * 32 + c4) = b1;
        __syncthreads();

        bf16x8 af[4], bfr[4];
#pragma unroll
        for (int i = 0; i < 4; i++)
            af[i] = *(const bf16x8*)(As + (wm + i * 16 + fr) * 32 + kg);
#pragma unroll
        for (int j = 0; j < 4; j++)
            bfr[j] = *(const bf16x8*)(Bs + (wn + j * 16 + fr) * 32 + kg);
#pragma unroll
        for (int i = 0; i < 4; i++)
#pragma unroll
            for (int j = 0; j < 4; j++)
                acc[i][j] = __builtin_amdgcn_mfma_f32_16x16x32_bf16(af[i], bfr[j], acc[i][j], 0, 0, 0);
    }

    // epilogue: C/D layout col=lane&15, row=(lane>>4)*4+reg
    const int cl = lane & 15;
    const int rq = (lane >> 4) * 4;
#pragma unroll
    for (int i = 0; i < 4; i++) {
#pragma unroll
        for (int j = 0; j < 4; j++) {
#pragma unroll
            for (int r = 0; r < 4; r++) {
                int row = bm + wm + i * 16 + rq + r;
                int col = bn + wn + j * 16 + cl;
                if (row < M && col < N) {
                    size_t o = strideC * blockIdx.z + (size_t)row * ldc + col;
                    if (OUT_BF16) ((us16*)Cv)[o] = f2b(acc[i][j][r]);
                    else          ((float*)Cv)[o] = acc[i][j][r];
                }
            }
        }
    }
}

// ---------------------------------------------------------------------------
// Scan phase 1: chunk sums, 5 c's per block (z = 0..1 -> c0 = 5z)
// ---------------------------------------------------------------------------
__global__ __launch_bounds__(256, 2)
void hrr_scan_sums(const float* __restrict__ Fall, const int* __restrict__ perms,
                   float* __restrict__ S) {
    const int n = blockIdx.x, b = blockIdx.y, c0 = blockIdx.z * 5;
    const int tid = threadIdx.x;
    __shared__ float kR[F_], kI[F_], vR[F_], vI[F_];

    float aR[5][3], aI[5][3];
    int gg[5][3];
#pragma unroll
    for (int cc = 0; cc < 5; cc++)
#pragma unroll
        for (int i = 0; i < 3; i++) {
            int f = tid + i * 256;
            aR[cc][i] = aI[cc][i] = 0.f;
            gg[cc][i] = (f < F_) ? perms[(c0 + cc) * F_ + f] : 0;
        }

    for (int tl = 0; tl < TC; tl++) {
        const int tt = b * T_ + n * TC + tl;
        const float* row = Fall + (size_t)tt * LF;
        __syncthreads();
        for (int j = tid; j < F_; j += 256) {
            kR[j] = row[2 * F_ + j]; kI[j] = row[3 * F_ + j];
            vR[j] = row[4 * F_ + j]; vI[j] = row[5 * F_ + j];
        }
        __syncthreads();
#pragma unroll
        for (int i = 0; i < 3; i++) {
            int f = tid + i * 256;
            if (f < F_) {
                float br = vR[f], bi = vI[f];
#pragma unroll
                for (int cc = 0; cc < 5; cc++) {
                    float ar = kR[gg[cc][i]], ai = kI[gg[cc][i]];
                    aR[cc][i] += ar * br - ai * bi;
                    aI[cc][i] += ar * bi + ai * br;
                }
            }
        }
    }
#pragma unroll
    for (int cc = 0; cc < 5; cc++)
#pragma unroll
        for (int i = 0; i < 3; i++) {
            int f = tid + i * 256;
            if (f < F_) {
                size_t a = ((((size_t)(c0 + cc) * B_ + b) * NCH + n) * F_ + f) * 2;
                S[a] = aR[cc][i]; S[a + 1] = aI[cc][i];
            }
        }
}

// ---------------------------------------------------------------------------
// Scan phase 2: exclusive prefix over chunks, per (c,b,f). In place.
// ---------------------------------------------------------------------------
__global__ void hrr_scan_prefix(float* __restrict__ S) {
    int tid = blockIdx.x * 256 + threadIdx.x;
    if (tid >= C_ * B_ * F_) return;
    int c = tid / (B_ * F_);
    int r = tid % (B_ * F_);
    int b = r / F_, f = r % F_;
    size_t base = (((size_t)c * B_ + b) * NCH) * F_ + f;
    float runR = 0.f, runI = 0.f;
    for (int n = 0; n < NCH; n++) {
        size_t a = (base + (size_t)n * F_) * 2;
        float tR = S[a], tI = S[a + 1];
        S[a] = runR; S[a + 1] = runI;
        runR += tR; runI += tI;
    }
}

// ---------------------------------------------------------------------------
// Scan phase 3: running kv state in regs, r = mean_c kv*conj(fqp) -> Rcat (bf16)
// ---------------------------------------------------------------------------
__global__ __launch_bounds__(512, 2)
void hrr_scan_apply(const float* __restrict__ Fall, const int* __restrict__ perms,
                    const float* __restrict__ S, us16* __restrict__ Rcat) {
    const int n = blockIdx.x, b = blockIdx.y;
    const int tid = threadIdx.x;
    __shared__ float qR[F_], qI[F_], kR[F_], kI[F_], vR[F_], vI[F_];

    float kvR[2][C_], kvI[2][C_];
    int gg[2][C_];
#pragma unroll
    for (int i = 0; i < 2; i++) {
        const int f = (i == 0) ? tid : 512;
        const bool act = (i == 0) || (tid == 0);
#pragma unroll
        for (int c = 0; c < C_; c++) {
            gg[i][c] = act ? perms[c * F_ + f] : 0;
            if (act) {
                size_t a = ((((size_t)c * B_ + b) * NCH + n) * F_ + f) * 2;
                kvR[i][c] = S[a]; kvI[i][c] = S[a + 1];
            } else { kvR[i][c] = 0.f; kvI[i][c] = 0.f; }
        }
    }

    for (int tl = 0; tl < TC; tl++) {
        const int tt = b * T_ + n * TC + tl;
        const float* row = Fall + (size_t)tt * LF;
        __syncthreads();
        for (int j = tid; j < F_; j += 512) {
            qR[j] = row[j];           qI[j] = row[F_ + j];
            kR[j] = row[2 * F_ + j];  kI[j] = row[3 * F_ + j];
            vR[j] = row[4 * F_ + j];  vI[j] = row[5 * F_ + j];
        }
        __syncthreads();
        us16* out = Rcat + (size_t)tt * KP2;
#pragma unroll
        for (int i = 0; i < 2; i++) {
            const int f = (i == 0) ? tid : 512;
            if (i == 0 || tid == 0) {
                float vr = vR[f], vi = vI[f];
                float accR = 0.f, accI = 0.f;
#pragma unroll
                for (int c = 0; c < C_; c++) {
                    int g = gg[i][c];
                    float ar = kR[g], ai = kI[g];
                    float nR = kvR[i][c] + ar * vr - ai * vi;
                    float nI = kvI[i][c] + ar * vi + ai * vr;
                    kvR[i][c] = nR; kvI[i][c] = nI;
                    float qr = qR[g], qi = qI[g];
                    accR += nR * qr + nI * qi;
                    accI += nI * qr - nR * qi;
                }
                out[f]        = f2b(accR * 0.1f);   // 1/C
                out[OIM2 + f] = f2b(accI * 0.1f);
            }
        }
    }
}

// ---------------------------------------------------------------------------
extern "C" void kernel_launch(void* const* d_in, const int* in_sizes, int n_in,
                              void* d_out, int out_size, void* d_ws, size_t ws_size,
                              hipStream_t stream) {
    const float* x  = (const float*)d_in[0];
    const float* Wq = (const float*)d_in[1];
    const float* Wk = (const float*)d_in[2];
    const float* Wv = (const float*)d_in[3];
    const float* Wo = (const float*)d_in[4];
    const int* perms = (const int*)d_in[5];
    float* out = (float*)d_out;

    char* ws = (char*)d_ws;
    us16* Xbf   = (us16*)(ws + O_XBF);
    us16* WT    = (us16*)(ws + O_WT);
    us16* WoBf  = (us16*)(ws + O_WOBF);
    us16* Tcs   = (us16*)(ws + O_TCS);
    us16* Sfb   = (us16*)(ws + O_SFB);
    us16* MallB = (us16*)(ws + O_MALLB);
    us16* MoutB = (us16*)(ws + O_MOUTB);
    us16* Rcat  = (us16*)(ws + O_RCAT);
    float* Fall = (float*)(ws + O_FALL);
    float* Ssc  = (float*)(ws + O_SSCAN);

    // prep: converts / transposes / trig matrices
    hrr_cvt_bf16<<<4096, 256, 0, stream>>>(x, Xbf, NTOK * D_ / 4);
    hrr_cvt_bf16<<<1024, 256, 0, stream>>>(Wo, WoBf, D_ * D_ / 4);
    hrr_transpose_bf16<<<dim3(32, 32, 3), 256, 0, stream>>>(Wq, Wk, Wv, WT);
    hrr_build_tcs<<<(1026 * 1024 + 255) / 256, 256, 0, stream>>>(Tcs);
    hrr_build_sfb<<<(KP2 * 1024 + 255) / 256, 256, 0, stream>>>(Sfb);

    // builder 1: Mall_w(1026x1024) = Tcs(1026x1024) @ WT_w(1024x1024)^T, bf16 out
    hrr_gemm_mfma<true><<<dim3(8, 9, 3), 256, 0, stream>>>(
        Tcs, WT, MallB, 1026, 1024, 1024, 1024, 1024, 1024,
        0, (size_t)D_ * D_, (size_t)1026 * 1024);

    // builder 2: MoutT(1024x1056) = Wo(1024x1024) @ S(1056x1024)^T, bf16 out
    hrr_gemm_mfma<true><<<dim3(9, 8, 1), 256, 0, stream>>>(
        WoBf, Sfb, MoutB, 1024, KP2, 1024, 1024, 1024, KP2, 0, 0, 0);

    // main GEMM: Fall(4096x3078) = Xbf @ MallB^T, fp32 out
    hrr_gemm_mfma<false><<<dim3(25, 32, 1), 256, 0, stream>>>(
        Xbf, MallB, Fall, NTOK, LF, 1024, 1024, 1024, LF, 0, 0, 0);

    // zero Rcat (pads must be 0; aliases prep region, builders done by now)
    hipMemsetAsync(Rcat, 0, (size_t)NTOK * KP2 * sizeof(us16), stream);

    // chunked causal scan
    hrr_scan_sums<<<dim3(NCH, B_, 2), 256, 0, stream>>>(Fall, perms, Ssc);
    hrr_scan_prefix<<<(C_ * B_ * F_ + 255) / 256, 256, 0, stream>>>(Ssc);
    hrr_scan_apply<<<dim3(NCH, B_), 512, 0, stream>>>(Fall, perms, Ssc, Rcat);

    // output GEMM: out(4096x1024) = Rcat(4096x1056) @ MoutB(1024x1056)^T, fp32
    hrr_gemm_mfma<false><<<dim3(8, 32, 1), 256, 0, stream>>>(
        Rcat, MoutB, out, NTOK, D_, KP2, KP2, KP2, D_, 0, 0, 0);
}

// Round 4
// 288.895 us; speedup vs baseline: 5.8111x; 1.0157x over previous
//
#include <hip/hip_runtime.h>
#include <math.h>

// Problem constants
#define B_   2
#define T_   2048
#define D_   1024
#define C_   10
#define F_   513
#define NTOK (B_ * T_)     // 4096 rows
#define LF   3078          // Fall stride = 6*F_ : [qR qI kR kI vR vI]
#define KP2  1056          // padded K for output GEMM (mult of 32)
#define OIM2 528           // Im block offset inside Rcat/MoutT (16-elem aligned)
#define NCH  128           // scan chunks
#define TC   (T_ / NCH)    // 16 timesteps per chunk

typedef unsigned short us16;
typedef __attribute__((ext_vector_type(8))) __bf16 bf16x8;
typedef __attribute__((ext_vector_type(4))) float  f32x4;

// Workspace layout (bytes) — total ~84.4 MB (proven budget: 90.4 MB in R2/R3)
#define O_XBF    ((size_t)0)                       // x bf16: 8,388,608
#define O_PREP   ((size_t)8388608)                 // WT(3x2MB)+Wo_bf(2MB)+Tcs = 10,489,856
#define O_WT     (O_PREP)
#define O_WOBF   (O_PREP + 6291456)
#define O_TCS    (O_PREP + 8388608)
#define O_RCAT   (O_PREP)                          // Rcat bf16 aliases PREP after builders
#define O_SFB    (O_PREP + 10489856)               // S trig: 2,162,688
#define O_MALLB  (O_SFB + 2162688)                 // Mall bf16: 6,303,744
#define O_MOUTB  (O_MALLB + 6303744)               // MoutT bf16: 2,162,688
#define O_FALL   (O_MOUTB + 2162688)               // Fall fp32: 50,429,952
#define O_SSCAN  (O_FALL + 50429952)               // scan sums fp32: 10,506,240

__device__ __forceinline__ us16 f2b(float f) {
    union { float f; unsigned u; } v; v.f = f;
    unsigned r = v.u + 0x7FFFu + ((v.u >> 16) & 1u);
    return (us16)(r >> 16);
}

// async global->LDS 16B copy (dest = wave-uniform base + lane*16B)
__device__ __forceinline__ void gl_lds16(const us16* g, us16* l) {
    __builtin_amdgcn_global_load_lds(
        (const __attribute__((address_space(1))) void*)g,
        (__attribute__((address_space(3))) void*)l, 16, 0, 0);
}

// ---------------------------------------------------------------------------
// float -> bf16 copy-convert (vectorized by 4)
// ---------------------------------------------------------------------------
__global__ void hrr_cvt_bf16(const float* __restrict__ in, us16* __restrict__ out, int n4) {
    int i = blockIdx.x * 256 + threadIdx.x;
    if (i < n4) {
        float4 v = ((const float4*)in)[i];
        ushort4 o;
        o.x = f2b(v.x); o.y = f2b(v.y); o.z = f2b(v.z); o.w = f2b(v.w);
        ((ushort4*)out)[i] = o;
    }
}

// ---------------------------------------------------------------------------
// Transpose W (1024x1024 fp32) -> bf16, 3 matrices via blockIdx.z
// ---------------------------------------------------------------------------
__global__ void hrr_transpose_bf16(const float* __restrict__ Wq,
                                   const float* __restrict__ Wk,
                                   const float* __restrict__ Wv,
                                   us16* __restrict__ WT) {
    const float* W = (blockIdx.z == 0) ? Wq : (blockIdx.z == 1) ? Wk : Wv;
    us16* O = WT + (size_t)blockIdx.z * D_ * D_;
    __shared__ float t[32][33];
    const int bx = blockIdx.x * 32, by = blockIdx.y * 32;
    const int tx = threadIdx.x & 31, ty = threadIdx.x >> 5;   // 32 x 8
#pragma unroll
    for (int i = 0; i < 32; i += 8)
        t[ty + i][tx] = W[(size_t)(by + ty + i) * D_ + bx + tx];
    __syncthreads();
#pragma unroll
    for (int i = 0; i < 32; i += 8)
        O[(size_t)(bx + ty + i) * D_ + by + tx] = f2b(t[tx][ty + i]);
}

// ---------------------------------------------------------------------------
// Tcs (1026 x 1024 bf16): rows 0..512 = cos(2*pi*f*e/1024); rows 513.. = -sin
// ---------------------------------------------------------------------------
__global__ void hrr_build_tcs(us16* __restrict__ Tcs) {
    int idx = blockIdx.x * 256 + threadIdx.x;
    if (idx >= 1026 * 1024) return;
    int r = idx >> 10, e = idx & 1023;
    int f = (r < F_) ? r : r - F_;
    int m = (f * e) & 1023;
    float ang = (float)m * 6.135923151542565e-3f;   // 2*pi/1024
    float v = (r < F_) ? cosf(ang) : -sinf(ang);
    Tcs[idx] = f2b(v);
}

// ---------------------------------------------------------------------------
// S (1056 x 1024 bf16): rows 0..512 = scale_f*cos ; rows 528..1040 = -scale_f*sin
// ---------------------------------------------------------------------------
__global__ void hrr_build_sfb(us16* __restrict__ S) {
    int idx = blockIdx.x * 256 + threadIdx.x;
    if (idx >= KP2 * 1024) return;
    int r = idx >> 10, e = idx & 1023;
    float v = 0.f;
    if (r < F_) {
        float scale = (r == 0 || r == 512) ? (1.0f / 1024.0f) : (2.0f / 1024.0f);
        v = scale * cosf((float)((r * e) & 1023) * 6.135923151542565e-3f);
    } else if (r >= OIM2 && r < OIM2 + F_) {
        int f = r - OIM2;
        float scale = (f == 0 || f == 512) ? (1.0f / 1024.0f) : (2.0f / 1024.0f);
        v = -scale * sinf((float)((f * e) & 1023) * 6.135923151542565e-3f);
    }
    S[idx] = f2b(v);
}

// ---------------------------------------------------------------------------
// bf16 MFMA GEMM (m97-style): C(MxN) = A(MxK) @ B(NxK)^T, bf16 row-major in.
// 128x128 tile, 256 threads (2x2 waves of 64x64), K-step 32, 16x16x32 MFMA.
// Staging via global_load_lds width=16 with rotate-swizzle LDS[r][s]=G[r][(s-r)&3]
// so ds_read_b128 fragment reads are 2-way-conflict (free). K mult 32, lda/ldb
// mult 8 elems. M/N edges: staging rows clamp, epilogue guards.
// ---------------------------------------------------------------------------
template <bool OUT_BF16>
__global__ __launch_bounds__(256, 3)
void hrr_gemm_mfma(const us16* __restrict__ Ab, const us16* __restrict__ Bb,
                   void* __restrict__ Cv, int M, int N, int K,
                   int lda, int ldb, int ldc,
                   size_t strideA, size_t strideB, size_t strideC) {
    const us16* A = Ab + strideA * blockIdx.z;
    const us16* B = Bb + strideB * blockIdx.z;

    __shared__ us16 As[128 * 32];
    __shared__ us16 Bs[128 * 32];

    const int tid  = threadIdx.x;
    const int lane = tid & 63;
    const int wave = tid >> 6;
    const int wm = (wave >> 1) * 64;
    const int wn = (wave & 1) * 64;
    const int bm = blockIdx.y * 128;
    const int bn = blockIdx.x * 128;

    // staging coords: wave covers 16 rows/round, lane -> (row = l/4, slot = l%4)
    const int rrel = lane >> 2;
    const int slot = lane & 3;
    const int trA  = wave * 16 + rrel;              // tile row (round base 0 / 64)
    const int cswz = ((slot - trA) & 3) * 8;        // swizzled k-offset (elems); +64 row keeps (mod 4)

    int ga0 = bm + trA;       if (ga0 >= M) ga0 = M - 1;
    int ga1 = bm + 64 + trA;  if (ga1 >= M) ga1 = M - 1;
    int gb0 = bn + trA;       if (gb0 >= N) gb0 = N - 1;
    int gb1 = bn + 64 + trA;  if (gb1 >= N) gb1 = N - 1;
    const us16* pA0 = A + (size_t)ga0 * lda + cswz;
    const us16* pA1 = A + (size_t)ga1 * lda + cswz;
    const us16* pB0 = B + (size_t)gb0 * ldb + cswz;
    const us16* pB1 = B + (size_t)gb1 * ldb + cswz;

    us16* lA0 = As + (wave * 16) * 32;              // wave-uniform LDS bases
    us16* lA1 = As + (64 + wave * 16) * 32;
    us16* lB0 = Bs + (wave * 16) * 32;
    us16* lB1 = Bs + (64 + wave * 16) * 32;

    f32x4 acc[4][4];
#pragma unroll
    for (int i = 0; i < 4; i++)
#pragma unroll
        for (int j = 0; j < 4; j++) acc[i][j] = (f32x4){0.f, 0.f, 0.f, 0.f};

    const int fr = lane & 15;
    const int q  = lane >> 4;                       // k-slot wanted (0..3)

    for (int k0 = 0; k0 < K; k0 += 32) {
        __syncthreads();                            // prior reads done before overwrite
        gl_lds16(pA0 + k0, lA0);
        gl_lds16(pA1 + k0, lA1);
        gl_lds16(pB0 + k0, lB0);
        gl_lds16(pB1 + k0, lB1);
        __syncthreads();                            // drains vmcnt (async LDS writes)

        bf16x8 af[4], bfr[4];
#pragma unroll
        for (int i = 0; i < 4; i++) {
            int r = wm + i * 16 + fr;
            af[i] = *(const bf16x8*)(As + r * 32 + (((q + r) & 3) * 8));
        }
#pragma unroll
        for (int j = 0; j < 4; j++) {
            int r = wn + j * 16 + fr;
            bfr[j] = *(const bf16x8*)(Bs + r * 32 + (((q + r) & 3) * 8));
        }
#pragma unroll
        for (int i = 0; i < 4; i++)
#pragma unroll
            for (int j = 0; j < 4; j++)
                acc[i][j] = __builtin_amdgcn_mfma_f32_16x16x32_bf16(af[i], bfr[j], acc[i][j], 0, 0, 0);
    }

    // epilogue: C/D layout col=lane&15, row=(lane>>4)*4+reg
    const int cl = lane & 15;
    const int rq = (lane >> 4) * 4;
#pragma unroll
    for (int i = 0; i < 4; i++) {
#pragma unroll
        for (int j = 0; j < 4; j++) {
#pragma unroll
            for (int r = 0; r < 4; r++) {
                int row = bm + wm + i * 16 + rq + r;
                int col = bn + wn + j * 16 + cl;
                if (row < M && col < N) {
                    size_t o = strideC * blockIdx.z + (size_t)row * ldc + col;
                    if (OUT_BF16) ((us16*)Cv)[o] = f2b(acc[i][j][r]);
                    else          ((float*)Cv)[o] = acc[i][j][r];
                }
            }
        }
    }
}

// ---------------------------------------------------------------------------
// Scan phase 1: chunk sums, ALL 10 c's per thread, 512 threads.
// k/v staged into LDS once per (n,b) timestep. Thread owns f=tid (+f=512 on t0).
// ---------------------------------------------------------------------------
__global__ __launch_bounds__(512, 2)
void hrr_scan_sums(const float* __restrict__ Fall, const int* __restrict__ perms,
                   float* __restrict__ S) {
    const int n = blockIdx.x, b = blockIdx.y;
    const int tid = threadIdx.x;
    __shared__ float kR[F_], kI[F_], vR[F_], vI[F_];

    float aR[2][C_], aI[2][C_];
    int gg[2][C_];
#pragma unroll
    for (int i = 0; i < 2; i++) {
        const int f = (i == 0) ? tid : 512;
        const bool act = (i == 0) || (tid == 0);
#pragma unroll
        for (int c = 0; c < C_; c++) {
            gg[i][c] = act ? perms[c * F_ + f] : 0;
            aR[i][c] = aI[i][c] = 0.f;
        }
    }

    for (int tl = 0; tl < TC; tl++) {
        const int tt = b * T_ + n * TC + tl;
        const float* row = Fall + (size_t)tt * LF;
        __syncthreads();
        for (int j = tid; j < F_; j += 512) {
            kR[j] = row[2 * F_ + j]; kI[j] = row[3 * F_ + j];
            vR[j] = row[4 * F_ + j]; vI[j] = row[5 * F_ + j];
        }
        __syncthreads();
#pragma unroll
        for (int i = 0; i < 2; i++) {
            const int f = (i == 0) ? tid : 512;
            if (i == 0 || tid == 0) {
                float br = vR[f], bi = vI[f];
#pragma unroll
                for (int c = 0; c < C_; c++) {
                    float ar = kR[gg[i][c]], ai = kI[gg[i][c]];
                    aR[i][c] += ar * br - ai * bi;
                    aI[i][c] += ar * bi + ai * br;
                }
            }
        }
    }
#pragma unroll
    for (int i = 0; i < 2; i++) {
        const int f = (i == 0) ? tid : 512;
        if (i == 0 || tid == 0) {
#pragma unroll
            for (int c = 0; c < C_; c++) {
                size_t a = ((((size_t)c * B_ + b) * NCH + n) * F_ + f) * 2;
                S[a] = aR[i][c]; S[a + 1] = aI[i][c];
            }
        }
    }
}

// ---------------------------------------------------------------------------
// Scan phase 2: exclusive prefix over chunks, per (c,b,f). 8-way unrolled
// loads hide the dependent-chain latency. In place.
// ---------------------------------------------------------------------------
__global__ void hrr_scan_prefix(float* __restrict__ S) {
    int tid = blockIdx.x * 256 + threadIdx.x;
    if (tid >= C_ * B_ * F_) return;
    int c = tid / (B_ * F_);
    int r = tid % (B_ * F_);
    int b = r / F_, f = r % F_;
    size_t base = (((size_t)c * B_ + b) * NCH) * F_ + f;
    float runR = 0.f, runI = 0.f;
    for (int n0 = 0; n0 < NCH; n0 += 8) {
        float tR[8], tI[8];
#pragma unroll
        for (int u = 0; u < 8; u++) {
            size_t a = (base + (size_t)(n0 + u) * F_) * 2;
            tR[u] = S[a]; tI[u] = S[a + 1];
        }
#pragma unroll
        for (int u = 0; u < 8; u++) {
            size_t a = (base + (size_t)(n0 + u) * F_) * 2;
            S[a] = runR; S[a + 1] = runI;
            runR += tR[u]; runI += tI[u];
        }
    }
}

// ---------------------------------------------------------------------------
// Scan phase 3: running kv state in regs, r = mean_c kv*conj(fqp) -> Rcat (bf16)
// ---------------------------------------------------------------------------
__global__ __launch_bounds__(512, 2)
void hrr_scan_apply(const float* __restrict__ Fall, const int* __restrict__ perms,
                    const float* __restrict__ S, us16* __restrict__ Rcat) {
    const int n = blockIdx.x, b = blockIdx.y;
    const int tid = threadIdx.x;
    __shared__ float qR[F_], qI[F_], kR[F_], kI[F_], vR[F_], vI[F_];

    float kvR[2][C_], kvI[2][C_];
    int gg[2][C_];
#pragma unroll
    for (int i = 0; i < 2; i++) {
        const int f = (i == 0) ? tid : 512;
        const bool act = (i == 0) || (tid == 0);
#pragma unroll
        for (int c = 0; c < C_; c++) {
            gg[i][c] = act ? perms[c * F_ + f] : 0;
            if (act) {
                size_t a = ((((size_t)c * B_ + b) * NCH + n) * F_ + f) * 2;
                kvR[i][c] = S[a]; kvI[i][c] = S[a + 1];
            } else { kvR[i][c] = 0.f; kvI[i][c] = 0.f; }
        }
    }

    for (int tl = 0; tl < TC; tl++) {
        const int tt = b * T_ + n * TC + tl;
        const float* row = Fall + (size_t)tt * LF;
        __syncthreads();
        for (int j = tid; j < F_; j += 512) {
            qR[j] = row[j];           qI[j] = row[F_ + j];
            kR[j] = row[2 * F_ + j];  kI[j] = row[3 * F_ + j];
            vR[j] = row[4 * F_ + j];  vI[j] = row[5 * F_ + j];
        }
        __syncthreads();
        us16* out = Rcat + (size_t)tt * KP2;
#pragma unroll
        for (int i = 0; i < 2; i++) {
            const int f = (i == 0) ? tid : 512;
            if (i == 0 || tid == 0) {
                float vr = vR[f], vi = vI[f];
                float accR = 0.f, accI = 0.f;
#pragma unroll
                for (int c = 0; c < C_; c++) {
                    int g = gg[i][c];
                    float ar = kR[g], ai = kI[g];
                    float nR = kvR[i][c] + ar * vr - ai * vi;
                    float nI = kvI[i][c] + ar * vi + ai * vr;
                    kvR[i][c] = nR; kvI[i][c] = nI;
                    float qr = qR[g], qi = qI[g];
                    accR += nR * qr + nI * qi;
                    accI += nI * qr - nR * qi;
                }
                out[f]        = f2b(accR * 0.1f);   // 1/C
                out[OIM2 + f] = f2b(accI * 0.1f);
            }
        }
    }
}

// ---------------------------------------------------------------------------
extern "C" void kernel_launch(void* const* d_in, const int* in_sizes, int n_in,
                              void* d_out, int out_size, void* d_ws, size_t ws_size,
                              hipStream_t stream) {
    const float* x  = (const float*)d_in[0];
    const float* Wq = (const float*)d_in[1];
    const float* Wk = (const float*)d_in[2];
    const float* Wv = (const float*)d_in[3];
    const float* Wo = (const float*)d_in[4];
    const int* perms = (const int*)d_in[5];
    float* out = (float*)d_out;

    char* ws = (char*)d_ws;
    us16* Xbf   = (us16*)(ws + O_XBF);
    us16* WT    = (us16*)(ws + O_WT);
    us16* WoBf  = (us16*)(ws + O_WOBF);
    us16* Tcs   = (us16*)(ws + O_TCS);
    us16* Sfb   = (us16*)(ws + O_SFB);
    us16* MallB = (us16*)(ws + O_MALLB);
    us16* MoutB = (us16*)(ws + O_MOUTB);
    us16* Rcat  = (us16*)(ws + O_RCAT);
    float* Fall = (float*)(ws + O_FALL);
    float* Ssc  = (float*)(ws + O_SSCAN);

    // prep: converts / transposes / trig matrices
    hrr_cvt_bf16<<<4096, 256, 0, stream>>>(x, Xbf, NTOK * D_ / 4);
    hrr_cvt_bf16<<<1024, 256, 0, stream>>>(Wo, WoBf, D_ * D_ / 4);
    hrr_transpose_bf16<<<dim3(32, 32, 3), 256, 0, stream>>>(Wq, Wk, Wv, WT);
    hrr_build_tcs<<<(1026 * 1024 + 255) / 256, 256, 0, stream>>>(Tcs);
    hrr_build_sfb<<<(KP2 * 1024 + 255) / 256, 256, 0, stream>>>(Sfb);

    // builder 1: Mall_w(1026x1024) = Tcs @ WT_w^T, bf16 out, batched over w
    hrr_gemm_mfma<true><<<dim3(8, 9, 3), 256, 0, stream>>>(
        Tcs, WT, MallB, 1026, 1024, 1024, 1024, 1024, 1024,
        0, (size_t)D_ * D_, (size_t)1026 * 1024);

    // builder 2: MoutT(1024x1056) = Wo @ S^T, bf16 out
    hrr_gemm_mfma<true><<<dim3(9, 8, 1), 256, 0, stream>>>(
        WoBf, Sfb, MoutB, 1024, KP2, 1024, 1024, 1024, KP2, 0, 0, 0);

    // main GEMM: Fall(4096x3078) = Xbf @ MallB^T, fp32 out
    hrr_gemm_mfma<false><<<dim3(25, 32, 1), 256, 0, stream>>>(
        Xbf, MallB, Fall, NTOK, LF, 1024, 1024, 1024, LF, 0, 0, 0);

    // zero Rcat (pads must be 0; aliases prep region, builders done by now)
    hipMemsetAsync(Rcat, 0, (size_t)NTOK * KP2 * sizeof(us16), stream);

    // chunked causal scan
    hrr_scan_sums<<<dim3(NCH, B_), 512, 0, stream>>>(Fall, perms, Ssc);
    hrr_scan_prefix<<<(C_ * B_ * F_ + 255) / 256, 256, 0, stream>>>(Ssc);
    hrr_scan_apply<<<dim3(NCH, B_), 512, 0, stream>>>(Fall, perms, Ssc, Rcat);

    // output GEMM: out(4096x1024) = Rcat(4096x1056) @ MoutB(1024x1056)^T, fp32
    hrr_gemm_mfma<false><<<dim3(8, 32, 1), 256, 0, stream>>>(
        Rcat, MoutB, out, NTOK, D_, KP2, KP2, KP2, D_, 0, 0, 0);
}